// Round 6
// baseline (234.178 us; speedup 1.0000x reference)
//
#include <hip/hip_runtime.h>
#include <cstdint>
#include <cstddef>

// ---------------------------------------------------------------------------
// Int8 GPT-2 attention block, MI355X (gfx950).
// All matmuls exact int8xint8->int32 via v_mfma_i32_16x16x64_i8.
// Round 6: c_attn GEMM re-tiled to block 256x128, wave-tile 128x64 (2x2
// waves), BK=64 dbuf. Wave-tile growth cuts LDS read bytes/MAC by 25%
// ((WM+WN)/(WM*WN): 1/32 -> 1/42.7) and LDS drops to 48 KB -> 3 blocks/CU
// resident (768-block grid), so barrier drains hide under cross-block TLP.
// Stride-64 b128 fragment reads are granule-uniform -> no swizzle needed.
// ---------------------------------------------------------------------------

typedef int v4i __attribute__((ext_vector_type(4)));

static constexpr float CATTN_ALPHA = 0.004f;
static constexpr float PV_ALPHA    = 0.002f;
static constexpr float PROJ_ALPHA  = 0.003f;
// (1e-4 / sqrt(128)) * log2(e):  exp(CE*x) == exp2(CE2*x)
static constexpr float CE2   = 1.275174308e-05f;
static constexpr float MAGIC = 12582912.0f;  // 2^23 + 2^22 (RNE round trick)

#define GLL16(gp, lp)                                              \
  __builtin_amdgcn_global_load_lds(                                \
      (const __attribute__((address_space(1))) void*)(gp),         \
      (__attribute__((address_space(3))) void*)(lp), 16, 0, 0)

__device__ __forceinline__ float exp2_fast(float x) {
#if __has_builtin(__builtin_amdgcn_exp2f)
  return __builtin_amdgcn_exp2f(x);
#else
  return __builtin_exp2f(x);
#endif
}

__device__ __forceinline__ uint32_t pack4(uint32_t u0, uint32_t u1, uint32_t u2,
                                          uint32_t u3) {
#if __has_builtin(__builtin_amdgcn_perm)
  uint32_t t01 = __builtin_amdgcn_perm(u1, u0, 0x00000400u);
  uint32_t t23 = __builtin_amdgcn_perm(u3, u2, 0x00000400u);
  return __builtin_amdgcn_perm(t23, t01, 0x05040100u);
#else
  return (u0 & 255u) | ((u1 & 255u) << 8) | ((u2 & 255u) << 16) | (u3 << 24);
#endif
}

// ---------------------------------------------------------------- quantize --
__global__ __launch_bounds__(256) void quant_kernel(const float* __restrict__ src,
                                                    int8_t* __restrict__ dst, int n4) {
  int i = blockIdx.x * 256 + threadIdx.x;
  if (i >= n4) return;
  float4 v = reinterpret_cast<const float4*>(src)[i];
  int b0 = __float2int_rn(v.x) & 255;
  int b1 = __float2int_rn(v.y) & 255;
  int b2 = __float2int_rn(v.z) & 255;
  int b3 = __float2int_rn(v.w) & 255;
  reinterpret_cast<int*>(dst)[i] = b0 | (b1 << 8) | (b2 << 16) | (b3 << 24);
}

// quantize + transpose: src f32 [K][N] -> dst i8 [N][K]   (64x64 tiles)
__global__ __launch_bounds__(256) void quant_transpose_kernel(const float* __restrict__ src,
                                                              int8_t* __restrict__ dst,
                                                              int K, int N) {
  __shared__ int8_t ts[64][68];
  const int k0 = blockIdx.x * 64, n0 = blockIdx.y * 64;
  const int t = threadIdx.x;
  for (int c = t; c < 1024; c += 256) {
    int r = c >> 4, cc = (c & 15) << 2;
    float4 v = *reinterpret_cast<const float4*>(&src[(size_t)(k0 + r) * N + n0 + cc]);
    int b0 = __float2int_rn(v.x) & 255;
    int b1 = __float2int_rn(v.y) & 255;
    int b2 = __float2int_rn(v.z) & 255;
    int b3 = __float2int_rn(v.w) & 255;
    *reinterpret_cast<int*>(&ts[r][cc]) = b0 | (b1 << 8) | (b2 << 16) | (b3 << 24);
  }
  __syncthreads();
  {
    int c = t;
    int rn = c >> 2, ck = (c & 3) << 4;
    __attribute__((aligned(16))) int8_t tmp[16];
#pragma unroll
    for (int j = 0; j < 16; ++j) tmp[j] = ts[ck + j][rn];
    *reinterpret_cast<v4i*>(&dst[(size_t)(n0 + rn) * K + k0 + ck]) =
        *reinterpret_cast<const v4i*>(tmp);
  }
}

// ------------------------------------------------------------- c_attn GEMM --
// A [4096][2048], BT [6144][2048]; block tile 256x128, wave tile 128x64
// (2x2 waves), BK=64, GLL dbuf (48 KB -> 3 blocks/CU).
// Epilogue: q,k row-major [bh][s][d]; v written TRANSPOSED [bh][d][s].
__global__ __launch_bounds__(256) void gemm_cattn_kernel(
    const int8_t* __restrict__ A, const int8_t* __restrict__ BT,
    const float* __restrict__ bias,
    int8_t* __restrict__ qout, int8_t* __restrict__ kout, int8_t* __restrict__ vtout) {
  __shared__ __align__(16) int8_t As[2][256][64];
  __shared__ __align__(16) int8_t Bs[2][128][64];
  const int t = threadIdx.x;
  const int lane = t & 63, wave = t >> 6;
  const int wr = wave >> 1, wc = wave & 1;
  const int l15 = lane & 15, l4 = lane >> 4;
  const int m0 = blockIdx.y * 256, n0 = blockIdx.x * 128;

  // staging (linear): each GLL16 covers 16 rows x 64 B
  const int srow = lane >> 2;          // 0..15
  const int scol = (lane & 3) << 4;    // 16B chunk
  const int8_t* ag = A + (size_t)(m0 + wave * 64 + srow) * 2048 + scol;
  const int8_t* bg = BT + (size_t)(n0 + wave * 32 + srow) * 2048 + scol;

  auto stage = [&](int b, int ki) {
    const int8_t* a_ = ag + ki * 64;
#pragma unroll
    for (int g = 0; g < 4; ++g)
      GLL16(a_ + (size_t)(g * 16) * 2048, &As[b][wave * 64 + g * 16][0]);
    const int8_t* b_ = bg + ki * 64;
#pragma unroll
    for (int g = 0; g < 2; ++g)
      GLL16(b_ + (size_t)(g * 16) * 2048, &Bs[b][wave * 32 + g * 16][0]);
  };

  v4i acc[8][4];
#pragma unroll
  for (int i = 0; i < 8; ++i)
#pragma unroll
    for (int j = 0; j < 4; ++j) acc[i][j] = (v4i){0, 0, 0, 0};

  const int aoff = (wr * 128 + l15) * 64 + l4 * 16;
  const int boff = (wc * 64 + l15) * 64 + l4 * 16;

  stage(0, 0);
  __syncthreads();
  for (int ki = 0; ki < 32; ++ki) {
    if (ki < 31) stage((ki + 1) & 1, ki + 1);
    const int8_t* ab = &As[ki & 1][0][0];
    const int8_t* bb = &Bs[ki & 1][0][0];
    v4i af[8], bf[4];
#pragma unroll
    for (int i = 0; i < 8; ++i)
      af[i] = *reinterpret_cast<const v4i*>(ab + aoff + i * 1024);
#pragma unroll
    for (int j = 0; j < 4; ++j)
      bf[j] = *reinterpret_cast<const v4i*>(bb + boff + j * 1024);
#pragma unroll
    for (int i = 0; i < 8; ++i)
#pragma unroll
      for (int j = 0; j < 4; ++j)
        acc[i][j] = __builtin_amdgcn_mfma_i32_16x16x64_i8(af[i], bf[j], acc[i][j], 0, 0, 0);
    __syncthreads();
  }

  // epilogue — which segment (q/k/v) is block-uniform (n-range is 128-aligned)
  const int which = n0 >> 11;
  const int hh = (n0 & 2047) >> 7;
  const int bi = m0 >> 11;
  const int s_base = m0 & 2047;  // batch-local row
  float bv[4];
#pragma unroll
  for (int j = 0; j < 4; ++j) bv[j] = bias[n0 + wc * 64 + j * 16 + l15];

  if (which == 2) {  // V -> transposed store [bh][d][s], 4 s-consecutive bytes/dword
    int8_t* vb = vtout + ((size_t)(bi * 16 + hh) * 128) * 2048;
#pragma unroll
    for (int i = 0; i < 8; ++i) {
#pragma unroll
      for (int j = 0; j < 4; ++j) {
        uint32_t w = 0;
#pragma unroll
        for (int rr = 0; rr < 4; ++rr) {
          float f = __fadd_rn(__fmul_rn(CATTN_ALPHA, (float)acc[i][j][rr]), bv[j]);
          f = rintf(f);
          f = fminf(fmaxf(f, -128.f), 127.f);
          w |= ((uint32_t)((int)f & 255)) << (rr * 8);
        }
        int d = wc * 64 + j * 16 + l15;
        int s0i = s_base + wr * 128 + i * 16 + l4 * 4;
        *reinterpret_cast<uint32_t*>(vb + (size_t)d * 2048 + s0i) = w;
      }
    }
  } else {
    int8_t* dst = (which == 0) ? qout : kout;
    int8_t* db = dst + ((size_t)(bi * 16 + hh) * 2048 + s_base) * 128;
#pragma unroll
    for (int i = 0; i < 8; ++i)
#pragma unroll
      for (int j = 0; j < 4; ++j)
#pragma unroll
        for (int rr = 0; rr < 4; ++rr) {
          float f = __fadd_rn(__fmul_rn(CATTN_ALPHA, (float)acc[i][j][rr]), bv[j]);
          f = rintf(f);
          f = fminf(fmaxf(f, -128.f), 127.f);
          int mo = wr * 128 + i * 16 + l4 * 4 + rr;
          int d = wc * 64 + j * 16 + l15;
          db[(size_t)mo * 128 + d] = (int8_t)(int)f;
        }
  }
}

// ------------------------------------------------------------- c_proj GEMM --
__global__ __launch_bounds__(256) void gemm_cproj_kernel(
    const int8_t* __restrict__ A, const int8_t* __restrict__ BT,
    const float* __restrict__ bias, float* __restrict__ out) {
  __shared__ __align__(16) int8_t As[2][128][128];
  __shared__ __align__(16) int8_t Bs[2][128][128];
  const int t = threadIdx.x;
  const int lane = t & 63, wave = t >> 6;
  const int wr = wave >> 1, wc = wave & 1;
  const int l15 = lane & 15, l4 = lane >> 4;
  const int m0 = blockIdx.y * 128, n0 = blockIdx.x * 128;

  const int srow = lane >> 3;
  const int scol = ((lane & 7) ^ srow) << 4;
  const int8_t* ag = A + (size_t)(m0 + wave * 32 + srow) * 2048 + scol;
  const int8_t* bg = BT + (size_t)(n0 + wave * 32 + srow) * 2048 + scol;

  auto stage = [&](int b, int ki) {
    const int8_t* a_ = ag + ki * 128;
    const int8_t* b_ = bg + ki * 128;
#pragma unroll
    for (int g = 0; g < 4; ++g) {
      GLL16(a_ + (size_t)(g * 8) * 2048, &As[b][wave * 32 + g * 8][0]);
      GLL16(b_ + (size_t)(g * 8) * 2048, &Bs[b][wave * 32 + g * 8][0]);
    }
  };

  v4i acc[4][4];
#pragma unroll
  for (int i = 0; i < 4; ++i)
#pragma unroll
    for (int j = 0; j < 4; ++j) acc[i][j] = (v4i){0, 0, 0, 0};

  const int rswz = (l4 ^ (l15 & 7)) << 4;
  const int aoff = (wr * 64 + l15) * 128 + rswz;
  const int boff = (wc * 64 + l15) * 128 + rswz;

  stage(0, 0);
  __syncthreads();
  for (int ki = 0; ki < 16; ++ki) {
    if (ki < 15) stage((ki + 1) & 1, ki + 1);
    const int8_t* ab = &As[ki & 1][0][0];
    const int8_t* bb = &Bs[ki & 1][0][0];
#pragma unroll
    for (int ks = 0; ks < 2; ++ks) {
      v4i af[4], bf[4];
#pragma unroll
      for (int i = 0; i < 4; ++i)
        af[i] = *reinterpret_cast<const v4i*>(ab + ((aoff + i * 2048) ^ (ks * 64)));
#pragma unroll
      for (int j = 0; j < 4; ++j)
        bf[j] = *reinterpret_cast<const v4i*>(bb + ((boff + j * 2048) ^ (ks * 64)));
#pragma unroll
      for (int i = 0; i < 4; ++i)
#pragma unroll
        for (int j = 0; j < 4; ++j)
          acc[i][j] = __builtin_amdgcn_mfma_i32_16x16x64_i8(af[i], bf[j], acc[i][j], 0, 0, 0);
    }
    __syncthreads();
  }
#pragma unroll
  for (int i = 0; i < 4; ++i)
#pragma unroll
    for (int j = 0; j < 4; ++j)
#pragma unroll
      for (int rr = 0; rr < 4; ++rr) {
        int m = m0 + wr * 64 + i * 16 + l4 * 4 + rr;
        int n = n0 + wc * 64 + j * 16 + l15;
        out[(size_t)m * 2048 + n] =
            __fadd_rn(__fmul_rn(PROJ_ALPHA, (float)acc[i][j][rr]), bias[n]);
      }
}

// --------------------------------------------------------------- attention --
// Block = (bh, 64 q-rows), 4 waves x 16 q-rows. S^T trick: mfma(A=K, B=Q)
// -> lane holds 16 k-values of ONE q row. No-max softmax (range-safe),
// hoisted 1/l, magic-number quantize, diagonal-tile-only masking.
// K/Q LDS rows (128B) chunk-XOR swizzled via pre-swizzled global source.
__global__ __launch_bounds__(256) void attn_kernel(
    const int8_t* __restrict__ Q, const int8_t* __restrict__ K8,
    const int8_t* __restrict__ VT, int8_t* __restrict__ O) {
  __shared__ __align__(16) int8_t q_s[64][128];
  __shared__ __align__(16) int8_t k_s[2][64][128];
  __shared__ __align__(16) int8_t vt_s[2][128][64];
  __shared__ __align__(16) int8_t p_s[64][80];

  const int t = threadIdx.x;
  const int lane = t & 63, wave = t >> 6;
  const int l15 = lane & 15, l4 = lane >> 4;
  const int bh = blockIdx.x;
  const int qt = (int)gridDim.y - 1 - (int)blockIdx.y;  // big blocks first
  const int r0 = qt * 64;
  const size_t kqbase = (size_t)bh * (2048 * 128);
  const size_t vtbase = (size_t)bh * (128 * 2048);

  // staging source offsets; K/Q use chunk-swizzle c_phys = c ^ (row&7)
  const int kq_go = ((lane >> 3) << 7) + ((((lane & 7) ^ (lane >> 3)) & 7) << 4);
  const int vt_go = ((lane >> 2) * 2048) + ((lane & 3) << 4);
  // fragment read offsets (swizzle applied on read)
  const int koff0 = (l15 << 7) + ((((0 + l4) ^ l15) & 7) << 4);
  const int koff1 = (l15 << 7) + ((((4 + l4) ^ l15) & 7) << 4);
  const int voff = l15 * 64 + l4 * 16;
  const int poff_w = (wave * 16 + l15) * 80 + l4 * 4;   // + ni*16
  const int poff_r = (wave * 16 + l15) * 80 + l4 * 16;

  // ---- stage Q + first K tile ----
  {
    const int8_t* qg = Q + kqbase + (size_t)(r0 + wave * 16) * 128 + kq_go;
    GLL16(qg, &q_s[wave * 16][0]);
    GLL16(qg + 8 * 128, &q_s[wave * 16 + 8][0]);
    const int8_t* kg = K8 + kqbase + (size_t)(wave * 16) * 128 + kq_go;
    GLL16(kg, &k_s[0][wave * 16][0]);
    GLL16(kg + 8 * 128, &k_s[0][wave * 16 + 8][0]);
  }
  __syncthreads();

  const v4i qf0 = *reinterpret_cast<const v4i*>(&q_s[0][0] + wave * 2048 + koff0);
  const v4i qf1 = *reinterpret_cast<const v4i*>(&q_s[0][0] + wave * 2048 + koff1);
  const int qgl = wave * 16 + l15;  // lane's q row minus r0

  float acc_l[4] = {0.f, 0.f, 0.f, 0.f};

  // ---- pass 1: sum of exp (no max needed: |logit| <= 18.5) ----
  for (int tt = 0; tt <= qt; ++tt) {
    if (tt < qt) {
      const int8_t* kg =
          K8 + kqbase + (size_t)((tt + 1) * 64 + wave * 16) * 128 + kq_go;
      GLL16(kg, &k_s[(tt + 1) & 1][wave * 16][0]);
      GLL16(kg + 8 * 128, &k_s[(tt + 1) & 1][wave * 16 + 8][0]);
    }
    const int8_t* kb = &k_s[tt & 1][0][0];
    v4i sacc[4];
#pragma unroll
    for (int ni = 0; ni < 4; ++ni) sacc[ni] = (v4i){0, 0, 0, 0};
#pragma unroll
    for (int ni = 0; ni < 4; ++ni) {
      v4i ak = *reinterpret_cast<const v4i*>(kb + ni * 2048 + koff0);
      sacc[ni] = __builtin_amdgcn_mfma_i32_16x16x64_i8(ak, qf0, sacc[ni], 0, 0, 0);
    }
#pragma unroll
    for (int ni = 0; ni < 4; ++ni) {
      v4i ak = *reinterpret_cast<const v4i*>(kb + ni * 2048 + koff1);
      sacc[ni] = __builtin_amdgcn_mfma_i32_16x16x64_i8(ak, qf1, sacc[ni], 0, 0, 0);
    }
    if (tt < qt) {  // fully unmasked tile (holds for every wave)
#pragma unroll
      for (int ni = 0; ni < 4; ++ni)
#pragma unroll
        for (int rr = 0; rr < 4; ++rr)
          acc_l[rr] += exp2_fast(CE2 * (float)sacc[ni][rr]);
    } else {  // diagonal tile: per-element causal mask
#pragma unroll
      for (int ni = 0; ni < 4; ++ni)
#pragma unroll
        for (int rr = 0; rr < 4; ++rr) {
          float e = exp2_fast(CE2 * (float)sacc[ni][rr]);
          acc_l[rr] += (ni * 16 + l4 * 4 + rr <= qgl) ? e : 0.f;
        }
    }
    __syncthreads();
  }
  float l_run = (acc_l[0] + acc_l[1]) + (acc_l[2] + acc_l[3]);
  l_run += __shfl_xor(l_run, 16);
  l_run += __shfl_xor(l_run, 32);
  const float inv = 127.0f / l_run;

  // ---- pass 2: recompute S^T, quantize P (magic RNE), PV ----
  {
    const int8_t* kg = K8 + kqbase + (size_t)(wave * 16) * 128 + kq_go;
    GLL16(kg, &k_s[0][wave * 16][0]);
    GLL16(kg + 8 * 128, &k_s[0][wave * 16 + 8][0]);
    const int8_t* vg = VT + vtbase + (size_t)(wave * 32) * 2048 + vt_go;
    GLL16(vg, &vt_s[0][wave * 32][0]);
    GLL16(vg + (size_t)16 * 2048, &vt_s[0][wave * 32 + 16][0]);
  }
  __syncthreads();

  v4i oacc[8];
#pragma unroll
  for (int nj = 0; nj < 8; ++nj) oacc[nj] = (v4i){0, 0, 0, 0};

  for (int tt = 0; tt <= qt; ++tt) {
    if (tt < qt) {
      const int kb1 = (tt + 1) * 64;
      const int8_t* kg = K8 + kqbase + (size_t)(kb1 + wave * 16) * 128 + kq_go;
      GLL16(kg, &k_s[(tt + 1) & 1][wave * 16][0]);
      GLL16(kg + 8 * 128, &k_s[(tt + 1) & 1][wave * 16 + 8][0]);
      const int8_t* vg = VT + vtbase + (size_t)(wave * 32) * 2048 + kb1 + vt_go;
      GLL16(vg, &vt_s[(tt + 1) & 1][wave * 32][0]);
      GLL16(vg + (size_t)16 * 2048, &vt_s[(tt + 1) & 1][wave * 32 + 16][0]);
    }
    const int8_t* kb = &k_s[tt & 1][0][0];
    v4i sacc[4];
#pragma unroll
    for (int ni = 0; ni < 4; ++ni) sacc[ni] = (v4i){0, 0, 0, 0};
#pragma unroll
    for (int ni = 0; ni < 4; ++ni) {
      v4i ak = *reinterpret_cast<const v4i*>(kb + ni * 2048 + koff0);
      sacc[ni] = __builtin_amdgcn_mfma_i32_16x16x64_i8(ak, qf0, sacc[ni], 0, 0, 0);
    }
#pragma unroll
    for (int ni = 0; ni < 4; ++ni) {
      v4i ak = *reinterpret_cast<const v4i*>(kb + ni * 2048 + koff1);
      sacc[ni] = __builtin_amdgcn_mfma_i32_16x16x64_i8(ak, qf1, sacc[ni], 0, 0, 0);
    }
    // quantize p = RNE(e * (127/l)) via magic number; pack 4 k-consecutive
    if (tt < qt) {
#pragma unroll
      for (int ni = 0; ni < 4; ++ni) {
        float f0 = fmaf(exp2_fast(CE2 * (float)sacc[ni][0]), inv, MAGIC);
        float f1 = fmaf(exp2_fast(CE2 * (float)sacc[ni][1]), inv, MAGIC);
        float f2 = fmaf(exp2_fast(CE2 * (float)sacc[ni][2]), inv, MAGIC);
        float f3 = fmaf(exp2_fast(CE2 * (float)sacc[ni][3]), inv, MAGIC);
        uint32_t w = pack4(__float_as_uint(f0), __float_as_uint(f1),
                           __float_as_uint(f2), __float_as_uint(f3));
        *reinterpret_cast<uint32_t*>(&p_s[0][0] + poff_w + ni * 16) = w;
      }
    } else {
#pragma unroll
      for (int ni = 0; ni < 4; ++ni) {
        float e0 = exp2_fast(CE2 * (float)sacc[ni][0]);
        float e1 = exp2_fast(CE2 * (float)sacc[ni][1]);
        float e2 = exp2_fast(CE2 * (float)sacc[ni][2]);
        float e3 = exp2_fast(CE2 * (float)sacc[ni][3]);
        int c = ni * 16 + l4 * 4;
        e0 = (c + 0 <= qgl) ? e0 : 0.f;
        e1 = (c + 1 <= qgl) ? e1 : 0.f;
        e2 = (c + 2 <= qgl) ? e2 : 0.f;
        e3 = (c + 3 <= qgl) ? e3 : 0.f;
        float f0 = fmaf(e0, inv, MAGIC), f1 = fmaf(e1, inv, MAGIC);
        float f2 = fmaf(e2, inv, MAGIC), f3 = fmaf(e3, inv, MAGIC);
        uint32_t w = pack4(__float_as_uint(f0), __float_as_uint(f1),
                           __float_as_uint(f2), __float_as_uint(f3));
        *reinterpret_cast<uint32_t*>(&p_s[0][0] + poff_w + ni * 16) = w;
      }
    }
    asm volatile("s_waitcnt lgkmcnt(0)" ::: "memory");
    v4i pf = *reinterpret_cast<const v4i*>(&p_s[0][0] + poff_r);
    const int8_t* vb = &vt_s[tt & 1][0][0];
#pragma unroll
    for (int nj = 0; nj < 8; ++nj) {
      v4i vf = *reinterpret_cast<const v4i*>(vb + nj * 1024 + voff);
      oacc[nj] = __builtin_amdgcn_mfma_i32_16x16x64_i8(pf, vf, oacc[nj], 0, 0, 0);
    }
    __syncthreads();
  }

  // epilogue: requant + merge-heads store ([B,S,E], e = h*128 + d)
  const int bq = bh >> 4, hh = bh & 15;
#pragma unroll
  for (int nj = 0; nj < 8; ++nj) {
#pragma unroll
    for (int rr = 0; rr < 4; ++rr) {
      int r = r0 + wave * 16 + l4 * 4 + rr;
      int d = nj * 16 + l15;
      float f = rintf(__fmul_rn(PV_ALPHA, (float)oacc[nj][rr]));
      f = fminf(fmaxf(f, -128.f), 127.f);
      O[((size_t)bq * 2048 + r) * 2048 + hh * 128 + d] = (int8_t)(int)f;
    }
  }
}

// ------------------------------------------------------------------ launch --
extern "C" void kernel_launch(void* const* d_in, const int* in_sizes, int n_in,
                              void* d_out, int out_size, void* d_ws, size_t ws_size,
                              hipStream_t stream) {
  const float* hs_f    = (const float*)d_in[0];
  const float* wattn_f = (const float*)d_in[1];
  const float* battn_f = (const float*)d_in[2];
  const float* wproj_f = (const float*)d_in[3];
  const float* bproj_f = (const float*)d_in[4];
  float* out_f = (float*)d_out;

  int8_t* ws = (int8_t*)d_ws;
  int8_t* hs_i8   = ws;                // 8 MB
  int8_t* wT_attn = ws + 8388608;      // 12 MB
  int8_t* wT_proj = ws + 20971520;     // 4 MB
  int8_t* q_i8    = ws + 25165824;     // 8 MB
  int8_t* k_i8    = ws + 33554432;     // 8 MB
  int8_t* vT_i8   = ws + 41943040;     // 8 MB  (written transposed by c_attn)
  int8_t* attn_i8 = ws + 50331648;     // 8 MB; end 58,720,256

  quant_kernel<<<dim3(8192), dim3(256), 0, stream>>>(hs_f, hs_i8, 2097152);
  quant_transpose_kernel<<<dim3(32, 96), dim3(256), 0, stream>>>(wattn_f, wT_attn, 2048, 6144);
  quant_transpose_kernel<<<dim3(32, 32), dim3(256), 0, stream>>>(wproj_f, wT_proj, 2048, 2048);
  gemm_cattn_kernel<<<dim3(48, 16), dim3(256), 0, stream>>>(hs_i8, wT_attn, battn_f,
                                                            q_i8, k_i8, vT_i8);
  attn_kernel<<<dim3(32, 32), dim3(256), 0, stream>>>(q_i8, k_i8, vT_i8, attn_i8);
  gemm_cproj_kernel<<<dim3(16, 32), dim3(256), 0, stream>>>(attn_i8, wT_proj, bproj_f, out_f);
}

// Round 7
// 168.286 us; speedup vs baseline: 1.3915x; 1.3915x over previous
//
#include <hip/hip_runtime.h>
#include <cstdint>
#include <cstddef>

// ---------------------------------------------------------------------------
// Int8 GPT-2 attention block, MI355X (gfx950).
// All matmuls exact int8xint8->int32 via v_mfma_i32_16x16x64_i8.
// Round 7: GEMMs back to the round-5 proven tiling (128x128, BK=128,
// 0-conflict XOR swizzle), now with COUNTED vmcnt (T4): stage(next) ->
// s_waitcnt vmcnt(8) -> s_barrier -> reads+MFMA -> s_barrier. Next tile's
// 8 global_load_lds stay in flight across the barrier (no full drain).
// Attention unchanged (counted-vmcnt port follows once GEMMs verify).
// ---------------------------------------------------------------------------

typedef int v4i __attribute__((ext_vector_type(4)));

static constexpr float CATTN_ALPHA = 0.004f;
static constexpr float PV_ALPHA    = 0.002f;
static constexpr float PROJ_ALPHA  = 0.003f;
// (1e-4 / sqrt(128)) * log2(e):  exp(CE*x) == exp2(CE2*x)
static constexpr float CE2   = 1.275174308e-05f;
static constexpr float MAGIC = 12582912.0f;  // 2^23 + 2^22 (RNE round trick)

#define GLL16(gp, lp)                                              \
  __builtin_amdgcn_global_load_lds(                                \
      (const __attribute__((address_space(1))) void*)(gp),         \
      (__attribute__((address_space(3))) void*)(lp), 16, 0, 0)

__device__ __forceinline__ float exp2_fast(float x) {
#if __has_builtin(__builtin_amdgcn_exp2f)
  return __builtin_amdgcn_exp2f(x);
#else
  return __builtin_exp2f(x);
#endif
}

__device__ __forceinline__ uint32_t pack4(uint32_t u0, uint32_t u1, uint32_t u2,
                                          uint32_t u3) {
#if __has_builtin(__builtin_amdgcn_perm)
  uint32_t t01 = __builtin_amdgcn_perm(u1, u0, 0x00000400u);
  uint32_t t23 = __builtin_amdgcn_perm(u3, u2, 0x00000400u);
  return __builtin_amdgcn_perm(t23, t01, 0x05040100u);
#else
  return (u0 & 255u) | ((u1 & 255u) << 8) | ((u2 & 255u) << 16) | (u3 << 24);
#endif
}

// ---------------------------------------------------------------- quantize --
__global__ __launch_bounds__(256) void quant_kernel(const float* __restrict__ src,
                                                    int8_t* __restrict__ dst, int n4) {
  int i = blockIdx.x * 256 + threadIdx.x;
  if (i >= n4) return;
  float4 v = reinterpret_cast<const float4*>(src)[i];
  int b0 = __float2int_rn(v.x) & 255;
  int b1 = __float2int_rn(v.y) & 255;
  int b2 = __float2int_rn(v.z) & 255;
  int b3 = __float2int_rn(v.w) & 255;
  reinterpret_cast<int*>(dst)[i] = b0 | (b1 << 8) | (b2 << 16) | (b3 << 24);
}

// quantize + transpose: src f32 [K][N] -> dst i8 [N][K]   (64x64 tiles)
__global__ __launch_bounds__(256) void quant_transpose_kernel(const float* __restrict__ src,
                                                              int8_t* __restrict__ dst,
                                                              int K, int N) {
  __shared__ int8_t ts[64][68];
  const int k0 = blockIdx.x * 64, n0 = blockIdx.y * 64;
  const int t = threadIdx.x;
  for (int c = t; c < 1024; c += 256) {
    int r = c >> 4, cc = (c & 15) << 2;
    float4 v = *reinterpret_cast<const float4*>(&src[(size_t)(k0 + r) * N + n0 + cc]);
    int b0 = __float2int_rn(v.x) & 255;
    int b1 = __float2int_rn(v.y) & 255;
    int b2 = __float2int_rn(v.z) & 255;
    int b3 = __float2int_rn(v.w) & 255;
    *reinterpret_cast<int*>(&ts[r][cc]) = b0 | (b1 << 8) | (b2 << 16) | (b3 << 24);
  }
  __syncthreads();
  {
    int c = t;
    int rn = c >> 2, ck = (c & 3) << 4;
    __attribute__((aligned(16))) int8_t tmp[16];
#pragma unroll
    for (int j = 0; j < 16; ++j) tmp[j] = ts[ck + j][rn];
    *reinterpret_cast<v4i*>(&dst[(size_t)(n0 + rn) * K + k0 + ck]) =
        *reinterpret_cast<const v4i*>(tmp);
  }
}

// ------------------------------------------------------------- c_attn GEMM --
// A [4096][2048], BT [6144][2048]; 128x128 tile, BK=128, GLL dbuf,
// chunk-XOR swizzled LDS (16B chunks, chunk ^= row&7), counted vmcnt.
// Epilogue: q,k row-major [bh][s][d]; v written TRANSPOSED [bh][d][s].
__global__ __launch_bounds__(256) void gemm_cattn_kernel(
    const int8_t* __restrict__ A, const int8_t* __restrict__ BT,
    const float* __restrict__ bias,
    int8_t* __restrict__ qout, int8_t* __restrict__ kout, int8_t* __restrict__ vtout) {
  __shared__ __align__(16) int8_t As[2][128][128];
  __shared__ __align__(16) int8_t Bs[2][128][128];
  const int t = threadIdx.x;
  const int lane = t & 63, wave = t >> 6;
  const int wr = wave >> 1, wc = wave & 1;
  const int l15 = lane & 15, l4 = lane >> 4;
  const int m0 = blockIdx.y * 128, n0 = blockIdx.x * 128;

  // staging: each GLL16 covers 8 rows x 128B; source col pre-swizzled so the
  // linear LDS write lands data at phys_chunk = log_chunk ^ (row&7).
  const int srow = lane >> 3;                    // 0..7
  const int scol = ((lane & 7) ^ srow) << 4;     // inverse-swizzled source chunk
  const int8_t* ag = A + (size_t)(m0 + wave * 32 + srow) * 2048 + scol;
  const int8_t* bg = BT + (size_t)(n0 + wave * 32 + srow) * 2048 + scol;

  auto stage = [&](int b, int ki) {
    const int8_t* a_ = ag + ki * 128;
    const int8_t* b_ = bg + ki * 128;
#pragma unroll
    for (int g = 0; g < 4; ++g) {
      GLL16(a_ + (size_t)(g * 8) * 2048, &As[b][wave * 32 + g * 8][0]);
      GLL16(b_ + (size_t)(g * 8) * 2048, &Bs[b][wave * 32 + g * 8][0]);
    }
  };

  v4i acc[4][4];
#pragma unroll
  for (int i = 0; i < 4; ++i)
#pragma unroll
    for (int j = 0; j < 4; ++j) acc[i][j] = (v4i){0, 0, 0, 0};

  // swizzled read offset: row r = (.. + l15), chunk = l4 (+4 for ks=1)
  const int rswz = (l4 ^ (l15 & 7)) << 4;
  const int aoff = (wr * 64 + l15) * 128 + rswz;
  const int boff = (wc * 64 + l15) * 128 + rswz;

  stage(0, 0);
  for (int ki = 0; ki < 16; ++ki) {
    if (ki < 15) {
      stage((ki + 1) & 1, ki + 1);   // 8 more in flight (16 total)
      asm volatile("s_waitcnt vmcnt(8)" ::: "memory");  // cur tile landed
    } else {
      asm volatile("s_waitcnt vmcnt(0)" ::: "memory");
    }
    __builtin_amdgcn_sched_barrier(0);
    __builtin_amdgcn_s_barrier();    // all waves' cur loads visible
    __builtin_amdgcn_sched_barrier(0);
    const int8_t* ab = &As[ki & 1][0][0];
    const int8_t* bb = &Bs[ki & 1][0][0];
#pragma unroll
    for (int ks = 0; ks < 2; ++ks) {
      v4i af[4], bf[4];
#pragma unroll
      for (int i = 0; i < 4; ++i)
        af[i] = *reinterpret_cast<const v4i*>(ab + ((aoff + i * 2048) ^ (ks * 64)));
#pragma unroll
      for (int j = 0; j < 4; ++j)
        bf[j] = *reinterpret_cast<const v4i*>(bb + ((boff + j * 2048) ^ (ks * 64)));
#pragma unroll
      for (int i = 0; i < 4; ++i)
#pragma unroll
        for (int j = 0; j < 4; ++j)
          acc[i][j] = __builtin_amdgcn_mfma_i32_16x16x64_i8(af[i], bf[j], acc[i][j], 0, 0, 0);
    }
    __builtin_amdgcn_sched_barrier(0);
    __builtin_amdgcn_s_barrier();    // reads done -> next stage may overwrite
  }

  // epilogue — which segment (q/k/v) is block-uniform (n-range is 128-aligned)
  const int which = n0 >> 11;
  const int hh = (n0 & 2047) >> 7;
  const int bi = m0 >> 11;
  const int s_base = m0 & 2047;  // batch-local row
  float bv[4];
#pragma unroll
  for (int j = 0; j < 4; ++j) bv[j] = bias[n0 + wc * 64 + j * 16 + l15];

  if (which == 2) {  // V -> transposed store [bh][d][s], 4 s-consecutive bytes/dword
    int8_t* vb = vtout + ((size_t)(bi * 16 + hh) * 128) * 2048;
#pragma unroll
    for (int i = 0; i < 4; ++i) {
#pragma unroll
      for (int j = 0; j < 4; ++j) {
        uint32_t w = 0;
#pragma unroll
        for (int rr = 0; rr < 4; ++rr) {
          float f = __fadd_rn(__fmul_rn(CATTN_ALPHA, (float)acc[i][j][rr]), bv[j]);
          f = rintf(f);
          f = fminf(fmaxf(f, -128.f), 127.f);
          w |= ((uint32_t)((int)f & 255)) << (rr * 8);
        }
        int d = wc * 64 + j * 16 + l15;
        int s0i = s_base + wr * 64 + i * 16 + l4 * 4;
        *reinterpret_cast<uint32_t*>(vb + (size_t)d * 2048 + s0i) = w;
      }
    }
  } else {
    int8_t* dst = (which == 0) ? qout : kout;
    int8_t* db = dst + ((size_t)(bi * 16 + hh) * 2048 + s_base) * 128;
#pragma unroll
    for (int i = 0; i < 4; ++i)
#pragma unroll
      for (int j = 0; j < 4; ++j)
#pragma unroll
        for (int rr = 0; rr < 4; ++rr) {
          float f = __fadd_rn(__fmul_rn(CATTN_ALPHA, (float)acc[i][j][rr]), bv[j]);
          f = rintf(f);
          f = fminf(fmaxf(f, -128.f), 127.f);
          int mo = wr * 64 + i * 16 + l4 * 4 + rr;
          int d = wc * 64 + j * 16 + l15;
          db[(size_t)mo * 128 + d] = (int8_t)(int)f;
        }
  }
}

// ------------------------------------------------------------- c_proj GEMM --
__global__ __launch_bounds__(256) void gemm_cproj_kernel(
    const int8_t* __restrict__ A, const int8_t* __restrict__ BT,
    const float* __restrict__ bias, float* __restrict__ out) {
  __shared__ __align__(16) int8_t As[2][128][128];
  __shared__ __align__(16) int8_t Bs[2][128][128];
  const int t = threadIdx.x;
  const int lane = t & 63, wave = t >> 6;
  const int wr = wave >> 1, wc = wave & 1;
  const int l15 = lane & 15, l4 = lane >> 4;
  const int m0 = blockIdx.y * 128, n0 = blockIdx.x * 128;

  const int srow = lane >> 3;
  const int scol = ((lane & 7) ^ srow) << 4;
  const int8_t* ag = A + (size_t)(m0 + wave * 32 + srow) * 2048 + scol;
  const int8_t* bg = BT + (size_t)(n0 + wave * 32 + srow) * 2048 + scol;

  auto stage = [&](int b, int ki) {
    const int8_t* a_ = ag + ki * 128;
    const int8_t* b_ = bg + ki * 128;
#pragma unroll
    for (int g = 0; g < 4; ++g) {
      GLL16(a_ + (size_t)(g * 8) * 2048, &As[b][wave * 32 + g * 8][0]);
      GLL16(b_ + (size_t)(g * 8) * 2048, &Bs[b][wave * 32 + g * 8][0]);
    }
  };

  v4i acc[4][4];
#pragma unroll
  for (int i = 0; i < 4; ++i)
#pragma unroll
    for (int j = 0; j < 4; ++j) acc[i][j] = (v4i){0, 0, 0, 0};

  const int rswz = (l4 ^ (l15 & 7)) << 4;
  const int aoff = (wr * 64 + l15) * 128 + rswz;
  const int boff = (wc * 64 + l15) * 128 + rswz;

  stage(0, 0);
  for (int ki = 0; ki < 16; ++ki) {
    if (ki < 15) {
      stage((ki + 1) & 1, ki + 1);
      asm volatile("s_waitcnt vmcnt(8)" ::: "memory");
    } else {
      asm volatile("s_waitcnt vmcnt(0)" ::: "memory");
    }
    __builtin_amdgcn_sched_barrier(0);
    __builtin_amdgcn_s_barrier();
    __builtin_amdgcn_sched_barrier(0);
    const int8_t* ab = &As[ki & 1][0][0];
    const int8_t* bb = &Bs[ki & 1][0][0];
#pragma unroll
    for (int ks = 0; ks < 2; ++ks) {
      v4i af[4], bf[4];
#pragma unroll
      for (int i = 0; i < 4; ++i)
        af[i] = *reinterpret_cast<const v4i*>(ab + ((aoff + i * 2048) ^ (ks * 64)));
#pragma unroll
      for (int j = 0; j < 4; ++j)
        bf[j] = *reinterpret_cast<const v4i*>(bb + ((boff + j * 2048) ^ (ks * 64)));
#pragma unroll
      for (int i = 0; i < 4; ++i)
#pragma unroll
        for (int j = 0; j < 4; ++j)
          acc[i][j] = __builtin_amdgcn_mfma_i32_16x16x64_i8(af[i], bf[j], acc[i][j], 0, 0, 0);
    }
    __builtin_amdgcn_sched_barrier(0);
    __builtin_amdgcn_s_barrier();
  }
#pragma unroll
  for (int i = 0; i < 4; ++i)
#pragma unroll
    for (int j = 0; j < 4; ++j)
#pragma unroll
      for (int rr = 0; rr < 4; ++rr) {
        int m = m0 + wr * 64 + i * 16 + l4 * 4 + rr;
        int n = n0 + wc * 64 + j * 16 + l15;
        out[(size_t)m * 2048 + n] =
            __fadd_rn(__fmul_rn(PROJ_ALPHA, (float)acc[i][j][rr]), bias[n]);
      }
}

// --------------------------------------------------------------- attention --
// Block = (bh, 64 q-rows), 4 waves x 16 q-rows. S^T trick: mfma(A=K, B=Q)
// -> lane holds 16 k-values of ONE q row. No-max softmax (range-safe),
// hoisted 1/l, magic-number quantize, diagonal-tile-only masking.
// K/Q LDS rows (128B) chunk-XOR swizzled via pre-swizzled global source.
__global__ __launch_bounds__(256) void attn_kernel(
    const int8_t* __restrict__ Q, const int8_t* __restrict__ K8,
    const int8_t* __restrict__ VT, int8_t* __restrict__ O) {
  __shared__ __align__(16) int8_t q_s[64][128];
  __shared__ __align__(16) int8_t k_s[2][64][128];
  __shared__ __align__(16) int8_t vt_s[2][128][64];
  __shared__ __align__(16) int8_t p_s[64][80];

  const int t = threadIdx.x;
  const int lane = t & 63, wave = t >> 6;
  const int l15 = lane & 15, l4 = lane >> 4;
  const int bh = blockIdx.x;
  const int qt = (int)gridDim.y - 1 - (int)blockIdx.y;  // big blocks first
  const int r0 = qt * 64;
  const size_t kqbase = (size_t)bh * (2048 * 128);
  const size_t vtbase = (size_t)bh * (128 * 2048);

  // staging source offsets; K/Q use chunk-swizzle c_phys = c ^ (row&7)
  const int kq_go = ((lane >> 3) << 7) + ((((lane & 7) ^ (lane >> 3)) & 7) << 4);
  const int vt_go = ((lane >> 2) * 2048) + ((lane & 3) << 4);
  // fragment read offsets (swizzle applied on read)
  const int koff0 = (l15 << 7) + ((((0 + l4) ^ l15) & 7) << 4);
  const int koff1 = (l15 << 7) + ((((4 + l4) ^ l15) & 7) << 4);
  const int voff = l15 * 64 + l4 * 16;
  const int poff_w = (wave * 16 + l15) * 80 + l4 * 4;   // + ni*16
  const int poff_r = (wave * 16 + l15) * 80 + l4 * 16;

  // ---- stage Q + first K tile ----
  {
    const int8_t* qg = Q + kqbase + (size_t)(r0 + wave * 16) * 128 + kq_go;
    GLL16(qg, &q_s[wave * 16][0]);
    GLL16(qg + 8 * 128, &q_s[wave * 16 + 8][0]);
    const int8_t* kg = K8 + kqbase + (size_t)(wave * 16) * 128 + kq_go;
    GLL16(kg, &k_s[0][wave * 16][0]);
    GLL16(kg + 8 * 128, &k_s[0][wave * 16 + 8][0]);
  }
  __syncthreads();

  const v4i qf0 = *reinterpret_cast<const v4i*>(&q_s[0][0] + wave * 2048 + koff0);
  const v4i qf1 = *reinterpret_cast<const v4i*>(&q_s[0][0] + wave * 2048 + koff1);
  const int qgl = wave * 16 + l15;  // lane's q row minus r0

  float acc_l[4] = {0.f, 0.f, 0.f, 0.f};

  // ---- pass 1: sum of exp (no max needed: |logit| <= 18.5) ----
  for (int tt = 0; tt <= qt; ++tt) {
    if (tt < qt) {
      const int8_t* kg =
          K8 + kqbase + (size_t)((tt + 1) * 64 + wave * 16) * 128 + kq_go;
      GLL16(kg, &k_s[(tt + 1) & 1][wave * 16][0]);
      GLL16(kg + 8 * 128, &k_s[(tt + 1) & 1][wave * 16 + 8][0]);
    }
    const int8_t* kb = &k_s[tt & 1][0][0];
    v4i sacc[4];
#pragma unroll
    for (int ni = 0; ni < 4; ++ni) sacc[ni] = (v4i){0, 0, 0, 0};
#pragma unroll
    for (int ni = 0; ni < 4; ++ni) {
      v4i ak = *reinterpret_cast<const v4i*>(kb + ni * 2048 + koff0);
      sacc[ni] = __builtin_amdgcn_mfma_i32_16x16x64_i8(ak, qf0, sacc[ni], 0, 0, 0);
    }
#pragma unroll
    for (int ni = 0; ni < 4; ++ni) {
      v4i ak = *reinterpret_cast<const v4i*>(kb + ni * 2048 + koff1);
      sacc[ni] = __builtin_amdgcn_mfma_i32_16x16x64_i8(ak, qf1, sacc[ni], 0, 0, 0);
    }
    if (tt < qt) {  // fully unmasked tile (holds for every wave)
#pragma unroll
      for (int ni = 0; ni < 4; ++ni)
#pragma unroll
        for (int rr = 0; rr < 4; ++rr)
          acc_l[rr] += exp2_fast(CE2 * (float)sacc[ni][rr]);
    } else {  // diagonal tile: per-element causal mask
#pragma unroll
      for (int ni = 0; ni < 4; ++ni)
#pragma unroll
        for (int rr = 0; rr < 4; ++rr) {
          float e = exp2_fast(CE2 * (float)sacc[ni][rr]);
          acc_l[rr] += (ni * 16 + l4 * 4 + rr <= qgl) ? e : 0.f;
        }
    }
    __syncthreads();
  }
  float l_run = (acc_l[0] + acc_l[1]) + (acc_l[2] + acc_l[3]);
  l_run += __shfl_xor(l_run, 16);
  l_run += __shfl_xor(l_run, 32);
  const float inv = 127.0f / l_run;

  // ---- pass 2: recompute S^T, quantize P (magic RNE), PV ----
  {
    const int8_t* kg = K8 + kqbase + (size_t)(wave * 16) * 128 + kq_go;
    GLL16(kg, &k_s[0][wave * 16][0]);
    GLL16(kg + 8 * 128, &k_s[0][wave * 16 + 8][0]);
    const int8_t* vg = VT + vtbase + (size_t)(wave * 32) * 2048 + vt_go;
    GLL16(vg, &vt_s[0][wave * 32][0]);
    GLL16(vg + (size_t)16 * 2048, &vt_s[0][wave * 32 + 16][0]);
  }
  __syncthreads();

  v4i oacc[8];
#pragma unroll
  for (int nj = 0; nj < 8; ++nj) oacc[nj] = (v4i){0, 0, 0, 0};

  for (int tt = 0; tt <= qt; ++tt) {
    if (tt < qt) {
      const int kb1 = (tt + 1) * 64;
      const int8_t* kg = K8 + kqbase + (size_t)(kb1 + wave * 16) * 128 + kq_go;
      GLL16(kg, &k_s[(tt + 1) & 1][wave * 16][0]);
      GLL16(kg + 8 * 128, &k_s[(tt + 1) & 1][wave * 16 + 8][0]);
      const int8_t* vg = VT + vtbase + (size_t)(wave * 32) * 2048 + kb1 + vt_go;
      GLL16(vg, &vt_s[(tt + 1) & 1][wave * 32][0]);
      GLL16(vg + (size_t)16 * 2048, &vt_s[(tt + 1) & 1][wave * 32 + 16][0]);
    }
    const int8_t* kb = &k_s[tt & 1][0][0];
    v4i sacc[4];
#pragma unroll
    for (int ni = 0; ni < 4; ++ni) sacc[ni] = (v4i){0, 0, 0, 0};
#pragma unroll
    for (int ni = 0; ni < 4; ++ni) {
      v4i ak = *reinterpret_cast<const v4i*>(kb + ni * 2048 + koff0);
      sacc[ni] = __builtin_amdgcn_mfma_i32_16x16x64_i8(ak, qf0, sacc[ni], 0, 0, 0);
    }
#pragma unroll
    for (int ni = 0; ni < 4; ++ni) {
      v4i ak = *reinterpret_cast<const v4i*>(kb + ni * 2048 + koff1);
      sacc[ni] = __builtin_amdgcn_mfma_i32_16x16x64_i8(ak, qf1, sacc[ni], 0, 0, 0);
    }
    // quantize p = RNE(e * (127/l)) via magic number; pack 4 k-consecutive
    if (tt < qt) {
#pragma unroll
      for (int ni = 0; ni < 4; ++ni) {
        float f0 = fmaf(exp2_fast(CE2 * (float)sacc[ni][0]), inv, MAGIC);
        float f1 = fmaf(exp2_fast(CE2 * (float)sacc[ni][1]), inv, MAGIC);
        float f2 = fmaf(exp2_fast(CE2 * (float)sacc[ni][2]), inv, MAGIC);
        float f3 = fmaf(exp2_fast(CE2 * (float)sacc[ni][3]), inv, MAGIC);
        uint32_t w = pack4(__float_as_uint(f0), __float_as_uint(f1),
                           __float_as_uint(f2), __float_as_uint(f3));
        *reinterpret_cast<uint32_t*>(&p_s[0][0] + poff_w + ni * 16) = w;
      }
    } else {
#pragma unroll
      for (int ni = 0; ni < 4; ++ni) {
        float e0 = exp2_fast(CE2 * (float)sacc[ni][0]);
        float e1 = exp2_fast(CE2 * (float)sacc[ni][1]);
        float e2 = exp2_fast(CE2 * (float)sacc[ni][2]);
        float e3 = exp2_fast(CE2 * (float)sacc[ni][3]);
        int c = ni * 16 + l4 * 4;
        e0 = (c + 0 <= qgl) ? e0 : 0.f;
        e1 = (c + 1 <= qgl) ? e1 : 0.f;
        e2 = (c + 2 <= qgl) ? e2 : 0.f;
        e3 = (c + 3 <= qgl) ? e3 : 0.f;
        float f0 = fmaf(e0, inv, MAGIC), f1 = fmaf(e1, inv, MAGIC);
        float f2 = fmaf(e2, inv, MAGIC), f3 = fmaf(e3, inv, MAGIC);
        uint32_t w = pack4(__float_as_uint(f0), __float_as_uint(f1),
                           __float_as_uint(f2), __float_as_uint(f3));
        *reinterpret_cast<uint32_t*>(&p_s[0][0] + poff_w + ni * 16) = w;
      }
    }
    asm volatile("s_waitcnt lgkmcnt(0)" ::: "memory");
    v4i pf = *reinterpret_cast<const v4i*>(&p_s[0][0] + poff_r);
    const int8_t* vb = &vt_s[tt & 1][0][0];
#pragma unroll
    for (int nj = 0; nj < 8; ++nj) {
      v4i vf = *reinterpret_cast<const v4i*>(vb + nj * 1024 + voff);
      oacc[nj] = __builtin_amdgcn_mfma_i32_16x16x64_i8(pf, vf, oacc[nj], 0, 0, 0);
    }
    __syncthreads();
  }

  // epilogue: requant + merge-heads store ([B,S,E], e = h*128 + d)
  const int bq = bh >> 4, hh = bh & 15;
#pragma unroll
  for (int nj = 0; nj < 8; ++nj) {
#pragma unroll
    for (int rr = 0; rr < 4; ++rr) {
      int r = r0 + wave * 16 + l4 * 4 + rr;
      int d = nj * 16 + l15;
      float f = rintf(__fmul_rn(PV_ALPHA, (float)oacc[nj][rr]));
      f = fminf(fmaxf(f, -128.f), 127.f);
      O[((size_t)bq * 2048 + r) * 2048 + hh * 128 + d] = (int8_t)(int)f;
    }
  }
}

// ------------------------------------------------------------------ launch --
extern "C" void kernel_launch(void* const* d_in, const int* in_sizes, int n_in,
                              void* d_out, int out_size, void* d_ws, size_t ws_size,
                              hipStream_t stream) {
  const float* hs_f    = (const float*)d_in[0];
  const float* wattn_f = (const float*)d_in[1];
  const float* battn_f = (const float*)d_in[2];
  const float* wproj_f = (const float*)d_in[3];
  const float* bproj_f = (const float*)d_in[4];
  float* out_f = (float*)d_out;

  int8_t* ws = (int8_t*)d_ws;
  int8_t* hs_i8   = ws;                // 8 MB
  int8_t* wT_attn = ws + 8388608;      // 12 MB
  int8_t* wT_proj = ws + 20971520;     // 4 MB
  int8_t* q_i8    = ws + 25165824;     // 8 MB
  int8_t* k_i8    = ws + 33554432;     // 8 MB
  int8_t* vT_i8   = ws + 41943040;     // 8 MB  (written transposed by c_attn)
  int8_t* attn_i8 = ws + 50331648;     // 8 MB; end 58,720,256

  quant_kernel<<<dim3(8192), dim3(256), 0, stream>>>(hs_f, hs_i8, 2097152);
  quant_transpose_kernel<<<dim3(32, 96), dim3(256), 0, stream>>>(wattn_f, wT_attn, 2048, 6144);
  quant_transpose_kernel<<<dim3(32, 32), dim3(256), 0, stream>>>(wproj_f, wT_proj, 2048, 2048);
  gemm_cattn_kernel<<<dim3(48, 32), dim3(256), 0, stream>>>(hs_i8, wT_attn, battn_f,
                                                            q_i8, k_i8, vT_i8);
  attn_kernel<<<dim3(32, 32), dim3(256), 0, stream>>>(q_i8, k_i8, vT_i8, attn_i8);
  gemm_cproj_kernel<<<dim3(16, 32), dim3(256), 0, stream>>>(attn_i8, wT_proj, bproj_f, out_f);
}